// Round 4
// baseline (481.262 us; speedup 1.0000x reference)
//
#include <hip/hip_runtime.h>
#include <stdint.h>
#include <math.h>

#define NN   8192
#define IND  256
#define HID  16
#define KN   6
#define CH   512      // j-rows staged per LDS chunk
#define RPW  4        // rows per wave in k2
#define LP   20       // padded LDS row stride in dwords (80B: uniform bank coverage)
#define JH   (NN/2)   // j-range half per block

__device__ __forceinline__ uint64_t kmax(uint64_t a, uint64_t b) { return a > b ? a : b; }
__device__ __forceinline__ uint64_t kmin(uint64_t a, uint64_t b) { return a < b ? a : b; }

// ---------------------------------------------------------------------------
// k1: h[i] = normalize(x[i] @ W^T + b), also zero rs[i].
// ---------------------------------------------------------------------------
__global__ __launch_bounds__(256) void k1_embed(const float* __restrict__ x,
                                                const float* __restrict__ W,
                                                const float* __restrict__ b,
                                                float* __restrict__ h,
                                                float* __restrict__ rs)
{
    const int lane = threadIdx.x & 63;
    const int wv   = threadIdx.x >> 6;
    const int row  = blockIdx.x * 4 + wv;

    const float4 xv = *(const float4*)(x + (size_t)row * IND + lane * 4);

    float acc[HID];
#pragma unroll
    for (int k = 0; k < HID; ++k) {
        const float4 wv4 = *(const float4*)(W + (size_t)k * IND + lane * 4);
        float v = xv.x * wv4.x + xv.y * wv4.y + xv.z * wv4.z + xv.w * wv4.w;
#pragma unroll
        for (int m = 32; m >= 1; m >>= 1) v += __shfl_xor(v, m, 64);
        acc[k] = v;
    }

    if (lane == 0) {
        float hv[HID];
        float ss = 0.f;
#pragma unroll
        for (int k = 0; k < HID; ++k) { hv[k] = acc[k] + b[k]; ss += hv[k] * hv[k]; }
        const float nrm = fmaxf(sqrtf(ss), 1e-12f);
#pragma unroll
        for (int k = 0; k < HID; ++k) hv[k] = hv[k] / nrm;
        float4* hp = (float4*)(h + (size_t)row * HID);
        hp[0] = make_float4(hv[0],  hv[1],  hv[2],  hv[3]);
        hp[1] = make_float4(hv[4],  hv[5],  hv[6],  hv[7]);
        hp[2] = make_float4(hv[8],  hv[9],  hv[10], hv[11]);
        hp[3] = make_float4(hv[12], hv[13], hv[14], hv[15]);
        rs[row] = 0.f;
    }
}

// ---------------------------------------------------------------------------
// k2: fused sim scan + per-half top-8. Block = 4 waves x RPW rows, scanning
// HALF the j-range (half = blockIdx.x & 1) for 2x occupancy. Hot path is pure
// fp32: sorted kv[8]/ki[8]; strict '>' reproduces (value desc, index asc)
// because scan order means new index > all list indices. Packs u64 keys only
// in the epilogue butterfly. Emits sorted top-8 key list per (half,row).
// ---------------------------------------------------------------------------
__global__ __launch_bounds__(256) void k2_topk(const float* __restrict__ h,
                                               uint64_t* __restrict__ pp)
{
    __shared__ float lds[CH][LP];   // 40 KB

    const int tid   = threadIdx.x;
    const int lane  = tid & 63;
    const int wv    = tid >> 6;
    const int half  = blockIdx.x & 1;
    const int row0  = (blockIdx.x >> 1) * (4 * RPW) + wv * RPW;
    const int jbase = half * JH;

    float hr[RPW][HID];
#pragma unroll
    for (int r = 0; r < RPW; ++r) {
        const float4* hp = (const float4*)(h + (size_t)(row0 + r) * HID);
        const float4 t0 = hp[0], t1 = hp[1], t2 = hp[2], t3 = hp[3];
        hr[r][0]=t0.x;  hr[r][1]=t0.y;  hr[r][2]=t0.z;  hr[r][3]=t0.w;
        hr[r][4]=t1.x;  hr[r][5]=t1.y;  hr[r][6]=t1.z;  hr[r][7]=t1.w;
        hr[r][8]=t2.x;  hr[r][9]=t2.y;  hr[r][10]=t2.z; hr[r][11]=t2.w;
        hr[r][12]=t3.x; hr[r][13]=t3.y; hr[r][14]=t3.z; hr[r][15]=t3.w;
    }

    float    kv[RPW][8];
    uint32_t ki[RPW][8];
    float    kv7[RPW];
#pragma unroll
    for (int r = 0; r < RPW; ++r) {
#pragma unroll
        for (int t = 0; t < 8; ++t) { kv[r][t] = -INFINITY; ki[r][t] = 0u; }
        kv7[r] = -INFINITY;
    }

    for (int cb = 0; cb < JH; cb += CH) {
        __syncthreads();
#pragma unroll
        for (int it = 0; it < (CH * HID / 4) / 256; ++it) {
            const int flat = it * 256 + tid;
            const int j = flat >> 2, q = flat & 3;
            *(float4*)&lds[j][q * 4] =
                *(const float4*)(h + (size_t)(jbase + cb + j) * HID + q * 4);
        }
        __syncthreads();

#pragma unroll 2
        for (int g = 0; g < CH / 64; ++g) {
            const int jr = g * 64 + lane;
            const float4 a0 = *(const float4*)&lds[jr][0];
            const float4 a1 = *(const float4*)&lds[jr][4];
            const float4 a2 = *(const float4*)&lds[jr][8];
            const float4 a3 = *(const float4*)&lds[jr][12];
            const uint32_t jg = (uint32_t)(jbase + cb + jr);
#pragma unroll
            for (int r = 0; r < RPW; ++r) {
                const float v = hr[r][0]*a0.x  + hr[r][1]*a0.y  + hr[r][2]*a0.z  + hr[r][3]*a0.w
                              + hr[r][4]*a1.x  + hr[r][5]*a1.y  + hr[r][6]*a1.z  + hr[r][7]*a1.w
                              + hr[r][8]*a2.x  + hr[r][9]*a2.y  + hr[r][10]*a2.z + hr[r][11]*a2.w
                              + hr[r][12]*a3.x + hr[r][13]*a3.y + hr[r][14]*a3.z + hr[r][15]*a3.w;
                if (__builtin_expect(v > kv7[r], 0)) {
                    kv[r][7] = v; ki[r][7] = jg;
#pragma unroll
                    for (int s = 7; s >= 1; --s) {      // bubble up, strict >
                        const bool sw = kv[r][s] > kv[r][s - 1];
                        const float    av = sw ? kv[r][s]     : kv[r][s - 1];
                        const float    bv = sw ? kv[r][s - 1] : kv[r][s];
                        const uint32_t ai = sw ? ki[r][s]     : ki[r][s - 1];
                        const uint32_t bi = sw ? ki[r][s - 1] : ki[r][s];
                        kv[r][s - 1] = av; kv[r][s] = bv;
                        ki[r][s - 1] = ai; ki[r][s] = bi;
                    }
                    kv7[r] = kv[r][7];
                }
            }
        }
    }

    // pack exact u64 keys (value-flip | ~idx) and butterfly-merge across lanes
    uint64_t lst[RPW][8];
#pragma unroll
    for (int r = 0; r < RPW; ++r)
#pragma unroll
        for (int t = 0; t < 8; ++t) {
            uint32_t u = __float_as_uint(kv[r][t]);
            u = (u & 0x80000000u) ? ~u : (u | 0x80000000u);
            lst[r][t] = ((uint64_t)u << 32) | (uint64_t)(~ki[r][t]);
        }

#pragma unroll
    for (int r = 0; r < RPW; ++r) {
#pragma unroll
        for (int m = 1; m < 64; m <<= 1) {
            uint64_t o[8];
#pragma unroll
            for (int t = 0; t < 8; ++t)
                o[t] = (uint64_t)__shfl_xor((unsigned long long)lst[r][t], m, 64);
            uint64_t X[8];
#pragma unroll
            for (int t = 0; t < 8; ++t) X[t] = kmax(lst[r][t], o[7 - t]);
#define CSWP(i, jx) { const uint64_t hi = kmax(X[i], X[jx]); const uint64_t lo = kmin(X[i], X[jx]); X[i] = hi; X[jx] = lo; }
            CSWP(0,4) CSWP(1,5) CSWP(2,6) CSWP(3,7)
            CSWP(0,2) CSWP(1,3) CSWP(4,6) CSWP(5,7)
            CSWP(0,1) CSWP(2,3) CSWP(4,5) CSWP(6,7)
#undef CSWP
#pragma unroll
            for (int t = 0; t < 8; ++t) lst[r][t] = X[t];
        }
    }

    if (lane == 0) {
#pragma unroll
        for (int r = 0; r < RPW; ++r) {
            uint64_t* dst = pp + ((size_t)half * NN + (row0 + r)) * 8;
#pragma unroll
            for (int t = 0; t < 8; ++t) dst[t] = lst[r][t];
        }
    }
}

// ---------------------------------------------------------------------------
// k2b: merge the two sorted half-lists per row; emit neighbor idx/val
// (rank 0 = self, dropped). One thread per row.
// ---------------------------------------------------------------------------
__global__ __launch_bounds__(256) void k2_merge(const uint64_t* __restrict__ pp,
                                                int* __restrict__ nbr_idx,
                                                float* __restrict__ nbr_val)
{
    const int row = blockIdx.x * 256 + threadIdx.x;
    const uint64_t* A = pp + (size_t)row * 8;
    const uint64_t* B = pp + ((size_t)NN + row) * 8;
    int ia = 0, ib = 0;
    uint64_t a = A[0], bk = B[0];
#pragma unroll
    for (int t = 0; t < 7; ++t) {
        uint64_t sel;
        if (a >= bk) { sel = a; ++ia; a = A[ia]; }
        else         { sel = bk; ++ib; bk = B[ib]; }
        if (t >= 1) {
            uint32_t u = (uint32_t)(sel >> 32);
            u = (u & 0x80000000u) ? (u & 0x7fffffffu) : ~u;
            nbr_val[(size_t)row * KN + (t - 1)] = __uint_as_float(u);
            nbr_idx[(size_t)row * KN + (t - 1)] = (int)~(uint32_t)sel;
        }
    }
}

// ---------------------------------------------------------------------------
// k3: zero-fill d_out — grid-stride, plain coherent float4 stores
// (nontemporal stores caused post-timing divergence with the L2-resident
//  atomics in k5 + harness poison memsets — keep everything coherent)
// ---------------------------------------------------------------------------
__global__ __launch_bounds__(256) void k3_zero(float4* __restrict__ out)
{
    const size_t base = (size_t)blockIdx.x * 1024 + threadIdx.x;
    const float4 z = make_float4(0.f, 0.f, 0.f, 0.f);
#pragma unroll
    for (int q = 0; q < 4; ++q)
        out[base + (size_t)q * 256] = z;
}

// ---------------------------------------------------------------------------
// k4: rs[i] = row sums of symmetrized sparse matrix
// ---------------------------------------------------------------------------
__global__ __launch_bounds__(256) void k4_rowsum(const int* __restrict__ nbr_idx,
                                                 const float* __restrict__ nbr_val,
                                                 float* __restrict__ rs)
{
    const int e = blockIdx.x * 256 + threadIdx.x;
    const int i = e / KN;
    const int j = nbr_idx[e];
    const float v = nbr_val[e] * 0.5f;
    atomicAdd(&rs[i], v);
    atomicAdd(&rs[j], v);
}

// ---------------------------------------------------------------------------
// k5: scatter normalized values into pre-zeroed dense output
// ---------------------------------------------------------------------------
__global__ __launch_bounds__(256) void k5_scatter(const int* __restrict__ nbr_idx,
                                                  const float* __restrict__ nbr_val,
                                                  const float* __restrict__ rs,
                                                  float* __restrict__ out)
{
    const int e = blockIdx.x * 256 + threadIdx.x;
    const int i = e / KN;
    const int j = nbr_idx[e];
    const float v = nbr_val[e] * 0.5f;
    const float wi = v / (rs[i] + 1e-8f);
    const float wj = v / (rs[j] + 1e-8f);
    atomicAdd(out + (size_t)i * NN + j, wi);
    atomicAdd(out + (size_t)j * NN + i, wj);
}

// ---------------------------------------------------------------------------
extern "C" void kernel_launch(void* const* d_in, const int* in_sizes, int n_in,
                              void* d_out, int out_size, void* d_ws, size_t ws_size,
                              hipStream_t stream)
{
    const float* x = (const float*)d_in[0];   // 8192 x 256
    const float* W = (const float*)d_in[1];   // 16 x 256
    const float* b = (const float*)d_in[2];   // 16
    float* out = (float*)d_out;               // 8192 x 8192

    // workspace layout (~2 MB); pp first for 8B alignment
    uint64_t* pp = (uint64_t*)d_ws;                 // 2*NN*8 keys
    float* h  = (float*)(pp + (size_t)2 * NN * 8);  // NN*HID
    float* rs = h + (size_t)NN * HID;               // NN
    float* nv = rs + NN;                            // NN*KN
    int*   ni = (int*)(nv + (size_t)NN * KN);       // NN*KN

    k1_embed <<<NN / 4,              256, 0, stream>>>(x, W, b, h, rs);
    k2_topk  <<<(NN / (4 * RPW)) * 2, 256, 0, stream>>>(h, pp);
    k2_merge <<<NN / 256,            256, 0, stream>>>(pp, ni, nv);
    k3_zero  <<<(int)(((size_t)NN * NN / 4) / 1024), 256, 0, stream>>>((float4*)out);
    k4_rowsum<<<(NN * KN) / 256,     256, 0, stream>>>(ni, nv, rs);
    k5_scatter<<<(NN * KN) / 256,    256, 0, stream>>>(ni, nv, rs, out);
}

// Round 5
// 441.431 us; speedup vs baseline: 1.0902x; 1.0902x over previous
//
#include <hip/hip_runtime.h>
#include <stdint.h>
#include <math.h>

#define NN   8192
#define IND  256
#define HID  16
#define KN   6
#define CH   512      // j-rows staged per LDS chunk
#define RPW  2        // rows per wave in k2 (kept low: total live regs < 100, no scratch spill)
#define LP   20       // padded LDS row stride in dwords (80B: uniform bank coverage)

__device__ __forceinline__ uint64_t kmax(uint64_t a, uint64_t b) { return a > b ? a : b; }
__device__ __forceinline__ uint64_t kmin(uint64_t a, uint64_t b) { return a < b ? a : b; }

// ---------------------------------------------------------------------------
// k1: h[i] = normalize(x[i] @ W^T + b), also zero rs[i].
// ---------------------------------------------------------------------------
__global__ __launch_bounds__(256) void k1_embed(const float* __restrict__ x,
                                                const float* __restrict__ W,
                                                const float* __restrict__ b,
                                                float* __restrict__ h,
                                                float* __restrict__ rs)
{
    const int lane = threadIdx.x & 63;
    const int wv   = threadIdx.x >> 6;
    const int row  = blockIdx.x * 4 + wv;

    const float4 xv = *(const float4*)(x + (size_t)row * IND + lane * 4);

    float acc[HID];
#pragma unroll
    for (int k = 0; k < HID; ++k) {
        const float4 wv4 = *(const float4*)(W + (size_t)k * IND + lane * 4);
        float v = xv.x * wv4.x + xv.y * wv4.y + xv.z * wv4.z + xv.w * wv4.w;
#pragma unroll
        for (int m = 32; m >= 1; m >>= 1) v += __shfl_xor(v, m, 64);
        acc[k] = v;
    }

    if (lane == 0) {
        float hv[HID];
        float ss = 0.f;
#pragma unroll
        for (int k = 0; k < HID; ++k) { hv[k] = acc[k] + b[k]; ss += hv[k] * hv[k]; }
        const float nrm = fmaxf(sqrtf(ss), 1e-12f);
#pragma unroll
        for (int k = 0; k < HID; ++k) hv[k] = hv[k] / nrm;
        float4* hp = (float4*)(h + (size_t)row * HID);
        hp[0] = make_float4(hv[0],  hv[1],  hv[2],  hv[3]);
        hp[1] = make_float4(hv[4],  hv[5],  hv[6],  hv[7]);
        hp[2] = make_float4(hv[8],  hv[9],  hv[10], hv[11]);
        hp[3] = make_float4(hv[12], hv[13], hv[14], hv[15]);
        rs[row] = 0.f;
    }
}

// ---------------------------------------------------------------------------
// k2: fused sim scan + top-8 (rank 0 = self, dropped). Block = 4 waves x
// RPW=2 rows, full j-range scan. Hot-path state per lane: hr 32 + kv 16 +
// ki 16 regs -> no scratch spill (the R4 killer: RPW=4 needed ~150 live regs
// against a 100-reg allocation -> scratch round-trips dominated runtime).
// Strict '>' + ascending scan reproduces jax (value desc, index asc)
// tie-break; exact u64 keys only in the epilogue butterfly.
// ---------------------------------------------------------------------------
__global__ __launch_bounds__(256) void k2_topk(const float* __restrict__ h,
                                               int* __restrict__ nbr_idx,
                                               float* __restrict__ nbr_val)
{
    __shared__ float lds[CH][LP];   // 40 KB

    const int tid  = threadIdx.x;
    const int lane = tid & 63;
    const int wv   = tid >> 6;
    const int row0 = blockIdx.x * (4 * RPW) + wv * RPW;

    float hr[RPW][HID];
#pragma unroll
    for (int r = 0; r < RPW; ++r) {
        const float4* hp = (const float4*)(h + (size_t)(row0 + r) * HID);
        const float4 t0 = hp[0], t1 = hp[1], t2 = hp[2], t3 = hp[3];
        hr[r][0]=t0.x;  hr[r][1]=t0.y;  hr[r][2]=t0.z;  hr[r][3]=t0.w;
        hr[r][4]=t1.x;  hr[r][5]=t1.y;  hr[r][6]=t1.z;  hr[r][7]=t1.w;
        hr[r][8]=t2.x;  hr[r][9]=t2.y;  hr[r][10]=t2.z; hr[r][11]=t2.w;
        hr[r][12]=t3.x; hr[r][13]=t3.y; hr[r][14]=t3.z; hr[r][15]=t3.w;
    }

    float    kv[RPW][8];
    uint32_t ki[RPW][8];
    float    kv7[RPW];
#pragma unroll
    for (int r = 0; r < RPW; ++r) {
#pragma unroll
        for (int t = 0; t < 8; ++t) { kv[r][t] = -INFINITY; ki[r][t] = 0u; }
        kv7[r] = -INFINITY;
    }

    for (int cb = 0; cb < NN; cb += CH) {
        __syncthreads();
#pragma unroll
        for (int it = 0; it < (CH * HID / 4) / 256; ++it) {
            const int flat = it * 256 + tid;
            const int j = flat >> 2, q = flat & 3;
            *(float4*)&lds[j][q * 4] =
                *(const float4*)(h + (size_t)(cb + j) * HID + q * 4);
        }
        __syncthreads();

#pragma unroll 2
        for (int g = 0; g < CH / 64; ++g) {
            const int jr = g * 64 + lane;
            const float4 a0 = *(const float4*)&lds[jr][0];
            const float4 a1 = *(const float4*)&lds[jr][4];
            const float4 a2 = *(const float4*)&lds[jr][8];
            const float4 a3 = *(const float4*)&lds[jr][12];
            const uint32_t jg = (uint32_t)(cb + jr);
#pragma unroll
            for (int r = 0; r < RPW; ++r) {
                const float v = hr[r][0]*a0.x  + hr[r][1]*a0.y  + hr[r][2]*a0.z  + hr[r][3]*a0.w
                              + hr[r][4]*a1.x  + hr[r][5]*a1.y  + hr[r][6]*a1.z  + hr[r][7]*a1.w
                              + hr[r][8]*a2.x  + hr[r][9]*a2.y  + hr[r][10]*a2.z + hr[r][11]*a2.w
                              + hr[r][12]*a3.x + hr[r][13]*a3.y + hr[r][14]*a3.z + hr[r][15]*a3.w;
                if (__builtin_expect(v > kv7[r], 0)) {
                    kv[r][7] = v; ki[r][7] = jg;
#pragma unroll
                    for (int s = 7; s >= 1; --s) {      // bubble up, strict >
                        const bool sw = kv[r][s] > kv[r][s - 1];
                        const float    av = sw ? kv[r][s]     : kv[r][s - 1];
                        const float    bv = sw ? kv[r][s - 1] : kv[r][s];
                        const uint32_t ai = sw ? ki[r][s]     : ki[r][s - 1];
                        const uint32_t bi = sw ? ki[r][s - 1] : ki[r][s];
                        kv[r][s - 1] = av; kv[r][s] = bv;
                        ki[r][s - 1] = ai; ki[r][s] = bi;
                    }
                    kv7[r] = kv[r][7];
                }
            }
        }
    }

    // pack exact u64 keys (value-flip | ~idx) and butterfly-merge across lanes
#pragma unroll
    for (int r = 0; r < RPW; ++r) {
        uint64_t lst[8];
#pragma unroll
        for (int t = 0; t < 8; ++t) {
            uint32_t u = __float_as_uint(kv[r][t]);
            u = (u & 0x80000000u) ? ~u : (u | 0x80000000u);
            lst[t] = ((uint64_t)u << 32) | (uint64_t)(~ki[r][t]);
        }

#pragma unroll
        for (int m = 1; m < 64; m <<= 1) {
            uint64_t o[8];
#pragma unroll
            for (int t = 0; t < 8; ++t)
                o[t] = (uint64_t)__shfl_xor((unsigned long long)lst[t], m, 64);
            uint64_t X[8];
#pragma unroll
            for (int t = 0; t < 8; ++t) X[t] = kmax(lst[t], o[7 - t]);
#define CSWP(i, jx) { const uint64_t hi = kmax(X[i], X[jx]); const uint64_t lo = kmin(X[i], X[jx]); X[i] = hi; X[jx] = lo; }
            CSWP(0,4) CSWP(1,5) CSWP(2,6) CSWP(3,7)
            CSWP(0,2) CSWP(1,3) CSWP(4,6) CSWP(5,7)
            CSWP(0,1) CSWP(2,3) CSWP(4,5) CSWP(6,7)
#undef CSWP
#pragma unroll
            for (int t = 0; t < 8; ++t) lst[t] = X[t];
        }

        if (lane == 0) {
            const int row = row0 + r;
#pragma unroll
            for (int t = 1; t <= KN; ++t) {          // ranks 1..6 (rank 0 = self)
                const uint64_t k = lst[t];
                uint32_t u = (uint32_t)(k >> 32);
                u = (u & 0x80000000u) ? (u & 0x7fffffffu) : ~u;  // un-flip
                nbr_val[(size_t)row * KN + (t - 1)] = __uint_as_float(u);
                nbr_idx[(size_t)row * KN + (t - 1)] = (int)~(uint32_t)k;
            }
        }
    }
}

// ---------------------------------------------------------------------------
// k3: zero-fill d_out — grid-stride, plain coherent float4 stores
// (nontemporal stores caused post-timing divergence in R3 — keep coherent)
// ---------------------------------------------------------------------------
__global__ __launch_bounds__(256) void k3_zero(float4* __restrict__ out)
{
    const size_t base = (size_t)blockIdx.x * 1024 + threadIdx.x;
    const float4 z = make_float4(0.f, 0.f, 0.f, 0.f);
#pragma unroll
    for (int q = 0; q < 4; ++q)
        out[base + (size_t)q * 256] = z;
}

// ---------------------------------------------------------------------------
// k4: rs[i] = row sums of symmetrized sparse matrix
// ---------------------------------------------------------------------------
__global__ __launch_bounds__(256) void k4_rowsum(const int* __restrict__ nbr_idx,
                                                 const float* __restrict__ nbr_val,
                                                 float* __restrict__ rs)
{
    const int e = blockIdx.x * 256 + threadIdx.x;
    const int i = e / KN;
    const int j = nbr_idx[e];
    const float v = nbr_val[e] * 0.5f;
    atomicAdd(&rs[i], v);
    atomicAdd(&rs[j], v);
}

// ---------------------------------------------------------------------------
// k5: scatter normalized values into pre-zeroed dense output
// ---------------------------------------------------------------------------
__global__ __launch_bounds__(256) void k5_scatter(const int* __restrict__ nbr_idx,
                                                  const float* __restrict__ nbr_val,
                                                  const float* __restrict__ rs,
                                                  float* __restrict__ out)
{
    const int e = blockIdx.x * 256 + threadIdx.x;
    const int i = e / KN;
    const int j = nbr_idx[e];
    const float v = nbr_val[e] * 0.5f;
    const float wi = v / (rs[i] + 1e-8f);
    const float wj = v / (rs[j] + 1e-8f);
    atomicAdd(out + (size_t)i * NN + j, wi);
    atomicAdd(out + (size_t)j * NN + i, wj);
}

// ---------------------------------------------------------------------------
extern "C" void kernel_launch(void* const* d_in, const int* in_sizes, int n_in,
                              void* d_out, int out_size, void* d_ws, size_t ws_size,
                              hipStream_t stream)
{
    const float* x = (const float*)d_in[0];   // 8192 x 256
    const float* W = (const float*)d_in[1];   // 16 x 256
    const float* b = (const float*)d_in[2];   // 16
    float* out = (float*)d_out;               // 8192 x 8192

    // workspace layout (~1 MB)
    float* h  = (float*)d_ws;                       // NN*HID
    float* rs = h + (size_t)NN * HID;               // NN
    float* nv = rs + NN;                            // NN*KN
    int*   ni = (int*)(nv + (size_t)NN * KN);       // NN*KN

    k1_embed <<<NN / 4,           256, 0, stream>>>(x, W, b, h, rs);
    k2_topk  <<<NN / (4 * RPW),   256, 0, stream>>>(h, ni, nv);
    k3_zero  <<<(int)(((size_t)NN * NN / 4) / 1024), 256, 0, stream>>>((float4*)out);
    k4_rowsum<<<(NN * KN) / 256,  256, 0, stream>>>(ni, nv, rs);
    k5_scatter<<<(NN * KN) / 256, 256, 0, stream>>>(ni, nv, rs, out);
}